// Round 2
// baseline (348.214 us; speedup 1.0000x reference)
//
#include <hip/hip_runtime.h>

#define SEGS 100
#define SEGP 101          // padded stride, coprime with 32 banks
#define C_TILE 4
#define BLOCK 1024

typedef float vfloat4 __attribute__((ext_vector_type(4)));

// order-preserving float->uint encoding (monotone: a<b <=> enc(a)<enc(b))
__device__ __forceinline__ unsigned enc_f32(float f) {
    unsigned u = __float_as_uint(f);
    return u ^ (unsigned)(((int)u >> 31) | 0x80000000);
}
__device__ __forceinline__ float dec_f32(unsigned u) {
    unsigned m = (u & 0x80000000u) ? 0x80000000u : 0xFFFFFFFFu;
    return __uint_as_float(u ^ m);
}

__global__ __launch_bounds__(BLOCK) void seg_max_kernel(
    const float* __restrict__ pf,    // (B, C, N)
    const int* __restrict__ labels,  // (B, N) int32
    float* __restrict__ out,         // (B*SEGS, C)
    int C, int N)
{
    // One accumulator row per channel in the tile; no replicas.
    // Atomics are rare (read-test-skip), so fewer cells = more
    // same-address read broadcasts (free) and fewer bank conflicts.
    __shared__ unsigned acc[C_TILE * SEGP];   // 1.6 KB

    const int tid = threadIdx.x;
    const int tiles_per_b = C / C_TILE;             // 32
    const int b = blockIdx.x / tiles_per_b;
    const int c_base = (blockIdx.x % tiles_per_b) * C_TILE;

    // init accumulators to enc(-inf) = 0x007FFFFF
    for (int i = tid; i < C_TILE * SEGP; i += BLOCK) acc[i] = 0x007FFFFFu;
    __syncthreads();

    const int wave  = tid >> 6;
    const int lane  = tid & 63;
    const int cl    = wave & (C_TILE - 1);   // channel within tile (0..3)
    const int strip = wave >> 2;             // n-stripe (0..3)
    const int c     = c_base + cl;

    const vfloat4* pf4  = (const vfloat4*)(pf + ((size_t)b * C + c) * (size_t)N);
    const int4*    lb4  = (const int4*)(labels + (size_t)b * N);
    unsigned*      accc = acc + cl * SEGP;

    const int iters = N / 4 / 256;           // 64: float4 groups per (strip,lane)

    #pragma unroll 8
    for (int it = 0; it < iters; ++it) {
        int idx4 = it * 256 + strip * 64 + lane;
        vfloat4 f = __builtin_nontemporal_load(&pf4[idx4]);  // streamed once, skip L2
        int4 l4   = lb4[idx4];                               // L1/L2-hot shared stream

        unsigned e0 = enc_f32(f.x), e1 = enc_f32(f.y),
                 e2 = enc_f32(f.z), e3 = enc_f32(f.w);

        // snapshot reads: bank-parallel ds_read_b32, same-address broadcasts free.
        // monotone cells => skipping when e <= snapshot is always safe;
        // a stale-low snapshot only costs a redundant (still-correct) atomic.
        unsigned m0 = accc[l4.x], m1 = accc[l4.y],
                 m2 = accc[l4.z], m3 = accc[l4.w];

        if (e0 > m0) atomicMax(&accc[l4.x], e0);
        if (e1 > m1) atomicMax(&accc[l4.y], e1);
        if (e2 > m2) atomicMax(&accc[l4.z], e2);
        if (e3 > m3) atomicMax(&accc[l4.w], e3);
    }

    __syncthreads();
    // write out: 400 cells per block, no replica reduction needed
    if (tid < C_TILE * SEGS) {
        int ocl = tid & (C_TILE - 1);
        int l   = tid >> 2;
        out[((size_t)(b * SEGS + l)) * C + c_base + ocl] = dec_f32(acc[ocl * SEGP + l]);
    }
}

extern "C" void kernel_launch(void* const* d_in, const int* in_sizes, int n_in,
                              void* d_out, int out_size, void* d_ws, size_t ws_size,
                              hipStream_t stream) {
    const float* pf  = (const float*)d_in[0];   // (B, C, N) fp32
    const int*   lab = (const int*)d_in[2];     // (B, N) int32
    float*       out = (float*)d_out;           // (B*SEGS, C) fp32

    const long long bn = in_sizes[2];           // B*N
    const int C = (int)(in_sizes[0] / bn);      // 128
    const int B = out_size / (SEGS * C);        // 8
    const int N = (int)(bn / B);                // 65536

    const int blocks = B * (C / C_TILE);        // 256
    seg_max_kernel<<<blocks, BLOCK, 0, stream>>>(pf, lab, out, C, N);
}

// Round 6
// 343.521 us; speedup vs baseline: 1.0137x; 1.0137x over previous
//
#include <hip/hip_runtime.h>

#define SEGS 100
#define SEGP 101          // padded stride, coprime with 32 banks
#define C_TILE 2
#define BLOCK 1024

typedef float vfloat4 __attribute__((ext_vector_type(4)));

// order-preserving float->uint encoding (monotone: a<b <=> enc(a)<enc(b))
__device__ __forceinline__ unsigned enc_f32(float f) {
    unsigned u = __float_as_uint(f);
    return u ^ (unsigned)(((int)u >> 31) | 0x80000000);
}
__device__ __forceinline__ float dec_f32(unsigned u) {
    unsigned m = (u & 0x80000000u) ? 0x80000000u : 0xFFFFFFFFu;
    return __uint_as_float(u ^ m);
}

// __launch_bounds__(1024, 8): 8 waves/EU min => VGPR<=64 => 2 blocks/CU
// co-resident (32 waves/CU = HW cap). unroll 4 keeps live VGPRs in budget.
__global__ __launch_bounds__(BLOCK, 8) void seg_max_kernel(
    const float* __restrict__ pf,    // (B, C, N)
    const int* __restrict__ labels,  // (B, N) int32
    float* __restrict__ out,         // (B*SEGS, C)
    int C, int N)
{
    __shared__ unsigned acc[C_TILE * SEGP];   // 808 B

    const int tid = threadIdx.x;
    const int tiles_per_b = C / C_TILE;             // 64
    const int b = blockIdx.x / tiles_per_b;
    const int c_base = (blockIdx.x % tiles_per_b) * C_TILE;

    // init accumulators to enc(-inf) = 0x007FFFFF
    if (tid < C_TILE * SEGP) acc[tid] = 0x007FFFFFu;
    __syncthreads();

    const int wave  = tid >> 6;
    const int lane  = tid & 63;
    const int cl    = wave & (C_TILE - 1);   // channel within tile (0..1)
    const int strip = wave >> 1;             // n-stripe (0..7)
    const int c     = c_base + cl;

    const vfloat4* pf4  = (const vfloat4*)(pf + ((size_t)b * C + c) * (size_t)N);
    const int4*    lb4  = (const int4*)(labels + (size_t)b * N);
    unsigned*      accc = acc + cl * SEGP;

    const int iters = N / 4 / (8 * 64);      // 32 float4 groups per (strip,lane)

    #pragma unroll 4
    for (int it = 0; it < iters; ++it) {
        int idx4 = it * 512 + strip * 64 + lane;
        vfloat4 f = __builtin_nontemporal_load(&pf4[idx4]);  // streamed once
        int4 l4   = lb4[idx4];                               // L1/L2-hot shared stream

        unsigned e0 = enc_f32(f.x), e1 = enc_f32(f.y),
                 e2 = enc_f32(f.z), e3 = enc_f32(f.w);

        // snapshot reads: bank-parallel ds_read_b32; monotone cells =>
        // skipping when e <= snapshot is always safe; stale-low snapshot
        // only costs a redundant (still-correct) atomic.
        unsigned m0 = accc[l4.x], m1 = accc[l4.y],
                 m2 = accc[l4.z], m3 = accc[l4.w];

        if (e0 > m0) atomicMax(&accc[l4.x], e0);
        if (e1 > m1) atomicMax(&accc[l4.y], e1);
        if (e2 > m2) atomicMax(&accc[l4.z], e2);
        if (e3 > m3) atomicMax(&accc[l4.w], e3);
    }

    __syncthreads();
    // write out: 200 cells per block
    if (tid < C_TILE * SEGS) {
        int ocl = tid & (C_TILE - 1);
        int l   = tid >> 1;
        out[((size_t)(b * SEGS + l)) * C + c_base + ocl] = dec_f32(acc[ocl * SEGP + l]);
    }
}

extern "C" void kernel_launch(void* const* d_in, const int* in_sizes, int n_in,
                              void* d_out, int out_size, void* d_ws, size_t ws_size,
                              hipStream_t stream) {
    const float* pf  = (const float*)d_in[0];   // (B, C, N) fp32
    const int*   lab = (const int*)d_in[2];     // (B, N) int32
    float*       out = (float*)d_out;           // (B*SEGS, C) fp32

    const long long bn = in_sizes[2];           // B*N
    const int C = (int)(in_sizes[0] / bn);      // 128
    const int B = out_size / (SEGS * C);        // 8
    const int N = (int)(bn / B);                // 65536

    const int blocks = B * (C / C_TILE);        // 512 -> 2 blocks/CU
    seg_max_kernel<<<blocks, BLOCK, 0, stream>>>(pf, lab, out, C, N);
}